// Round 6
// baseline (397.794 us; speedup 1.0000x reference)
//
#include <hip/hip_runtime.h>
#include <cmath>

typedef __bf16 bf16_t;
typedef __bf16 bf16x8 __attribute__((ext_vector_type(8)));
typedef __bf16 bf16x4 __attribute__((ext_vector_type(4)));
typedef float f32x4 __attribute__((ext_vector_type(4)));

#define T_SEQ 2048
#define C_DIM 2048
#define H_NUM 16
#define HD    128
#define KK    2048  // reduction dim for both GEMMs

// async global->LDS, 16B per lane; dest = wave-uniform base + lane*16
#define GLOAD_LDS16(gaddr, laddr)                                          \
  __builtin_amdgcn_global_load_lds(                                        \
      (const __attribute__((address_space(1))) void*)(gaddr),              \
      (__attribute__((address_space(3))) void*)(laddr), 16, 0, 0)

#define BARR   asm volatile("s_barrier" ::: "memory")
#define VMCNT4 asm volatile("s_waitcnt vmcnt(4)" ::: "memory")
#define VMCNT0 asm volatile("s_waitcnt vmcnt(0)" ::: "memory")

// ---------------- RoPE cos/sin table: [T][64] ----------------
__global__ void rope_table_kernel(float* __restrict__ ct, float* __restrict__ st) {
  int idx = blockIdx.x * 256 + threadIdx.x;   // T*64 = 131072
  int t = idx >> 6, i = idx & 63;
  double invf = pow(10000.0, -(double)i / 64.0);  // base^(-2i/hd)
  float ang = (float)t * (float)invf;             // fp32 rounding like reference
  ct[idx] = cosf(ang);
  st[idx] = sinf(ang);
}

// ---------------- fp32 -> bf16 elementwise ----------------
__global__ void convert_bf16_kernel(const float* __restrict__ in, bf16_t* __restrict__ out, int n4) {
  int i = blockIdx.x * 256 + threadIdx.x;
  if (i >= n4) return;
  const float4 v = reinterpret_cast<const float4*>(in)[i];
  bf16x4 o;
  o[0] = (bf16_t)v.x; o[1] = (bf16_t)v.y; o[2] = (bf16_t)v.z; o[3] = (bf16_t)v.w;
  reinterpret_cast<bf16x4*>(out)[i] = o;
}

// ---------------- transpose+convert: in[R][Cc] f32 -> out[Cc][R] bf16 ----------------
__global__ void transpose_convert_kernel(const float* __restrict__ in, bf16_t* __restrict__ out,
                                         int R, int Cc) {
  __shared__ __align__(16) bf16_t tile[32][33];
  int c0 = blockIdx.x * 32, r0 = blockIdx.y * 32;
  int tx = threadIdx.x, ty = threadIdx.y;
#pragma unroll
  for (int i = 0; i < 4; ++i)
    tile[ty + 8 * i][tx] = (bf16_t)in[(size_t)(r0 + ty + 8 * i) * Cc + c0 + tx];
  __syncthreads();
#pragma unroll
  for (int i = 0; i < 4; ++i)
    out[(size_t)(c0 + ty + 8 * i) * R + r0 + tx] = tile[tx][ty + 8 * i];
}

// =====================================================================
// 256x256 8-phase GEMM (m201 template, plain HIP):
//   A[M][K] bf16 @ Bt[N][K] bf16, BK=64, 8 waves (2M x 4N), 512 threads.
//   LDS 128KB: 2 dbuf x (A[256][64] + B[256][64]); even K-tiles in buf0,
//   odd in buf1. global_load_lds (linear dest) + pre-swizzled global source
//   + swizzled ds_read: chunk ^= row&7 (round-5-verified conflict-free).
//   Iteration i computes K-tiles 2i (P1-P4) and 2i+1 (P5-P8); stages one
//   half-tile per phase (2 gload_lds/wave); counted vmcnt(4) at P4/P8 only.
//   Stage slots (constraint-audited): A(2i+1)h0@P1, A(2i+1)h1@P2,
//   B(2i+2)h0@P3, B(2i+2)h1@P4, A(2i+2)h0@P5, A(2i+2)h1@P6,
//   B(2i+3)h0@P7, B(2i+3)h1@P8.  vmcnt(4) leaves exactly the 2 youngest
//   half-tiles outstanding -> current tile fully landed.
// MODE 0: qkv epilogue (RoPE q,k; v transposed).  MODE 1: fp32 out.
// =====================================================================

#define STAGE_A(KT, H)                                                        \
  do {                                                                        \
    _Pragma("unroll") for (int j = 0; j < 2; ++j) {                           \
      const size_t goff = (size_t)((H) * 128 + j * 64 + srow) * KK +          \
                          (size_t)(KT) * 64 + sch * 8;                        \
      GLOAD_LDS16(Ab + goff, (char*)&lA[(KT) & 1][(H) * 128 + j * 64 + w * 8][0]); \
    }                                                                         \
  } while (0)

#define STAGE_B(KT, H)                                                        \
  do {                                                                        \
    _Pragma("unroll") for (int j = 0; j < 2; ++j) {                           \
      const size_t goff = (size_t)((H) * 128 + j * 64 + srow) * KK +          \
                          (size_t)(KT) * 64 + sch * 8;                        \
      GLOAD_LDS16(Bb + goff, (char*)&lB[(KT) & 1][(H) * 128 + j * 64 + w * 8][0]); \
    }                                                                         \
  } while (0)

#define LDA_PH(BUF, MH)                                                       \
  do {                                                                        \
    _Pragma("unroll") for (int mi = 0; mi < 4; ++mi)                          \
      _Pragma("unroll") for (int ks = 0; ks < 2; ++ks)                        \
        areg[mi][ks] = *reinterpret_cast<const bf16x8*>(                      \
            &lA[BUF][wr * 128 + (MH) * 64 + mi * 16 + lr]                     \
               [((ks * 4 + lg) ^ (lr & 7)) * 8]);                             \
  } while (0)

#define LDB_PH(BUF, NH)                                                       \
  do {                                                                        \
    _Pragma("unroll") for (int ni = 0; ni < 2; ++ni)                          \
      _Pragma("unroll") for (int ks = 0; ks < 2; ++ks)                        \
        breg[NH][ni][ks] = *reinterpret_cast<const bf16x8*>(                  \
            &lB[BUF][wc * 64 + (NH) * 32 + ni * 16 + lr]                      \
               [((ks * 4 + lg) ^ (lr & 7)) * 8]);                             \
  } while (0)

#define MMA_PH(MH, NH)                                                        \
  do {                                                                        \
    __builtin_amdgcn_s_setprio(1);                                            \
    _Pragma("unroll") for (int mi = 0; mi < 4; ++mi)                          \
      _Pragma("unroll") for (int ni = 0; ni < 2; ++ni)                        \
        _Pragma("unroll") for (int ks = 0; ks < 2; ++ks)                      \
          acc[(MH) * 4 + mi][(NH) * 2 + ni] =                                 \
              __builtin_amdgcn_mfma_f32_16x16x32_bf16(                        \
                  areg[mi][ks], breg[NH][ni][ks],                             \
                  acc[(MH) * 4 + mi][(NH) * 2 + ni], 0, 0, 0);                \
    __builtin_amdgcn_s_setprio(0);                                            \
  } while (0)

template <int MODE>
__global__ __launch_bounds__(512, 2)
void gemm256_kernel(const bf16_t* __restrict__ A, const bf16_t* __restrict__ Bt,
                    float* __restrict__ outF,
                    bf16_t* __restrict__ qws, bf16_t* __restrict__ kws,
                    bf16_t* __restrict__ vtws,
                    const float* __restrict__ ctab, const float* __restrict__ stab,
                    int NBX) {
  const int tid = threadIdx.x;
  const int l = tid & 63, w = tid >> 6;
  const int wr = w >> 2, wc = w & 3;
  const int lg = l >> 4, lr = l & 15;

  // XCD-aware bijective swizzle (nwg % 8 == 0 for both launches)
  const int nwg = gridDim.x;
  const int cpx = nwg >> 3;
  const int wgid = (blockIdx.x & 7) * cpx + (blockIdx.x >> 3);
  const int bx = wgid % NBX, by = wgid / NBX;
  const int m0 = by * 256, n0 = bx * 256;

  __shared__ __align__(16) bf16_t lA[2][256][64];
  __shared__ __align__(16) bf16_t lB[2][256][64];

  f32x4 acc[8][4] = {};
  bf16x8 areg[4][2];
  bf16x8 breg[2][2][2];

  // staging geometry (round-5-verified): thread covers row (tid>>3) within a
  // 64-row instruction slab; LDS dest lane-linear; global chunk pre-swizzled
  // so LDS phys chunk p of row r holds global chunk p ^ (r&7).
  const int srow = tid >> 3;                 // 0..63
  const int sch  = (tid & 7) ^ (srow & 7);
  const bf16_t* Ab = A + (size_t)m0 * KK;
  const bf16_t* Bb = Bt + (size_t)n0 * KK;

  // prologue: T0 fully + T1's B halves; vmcnt(4) -> T0 landed
  STAGE_B(0, 0); STAGE_B(0, 1); STAGE_A(0, 0); STAGE_A(0, 1);
  STAGE_B(1, 0); STAGE_B(1, 1);
  VMCNT4; BARR;

#pragma unroll 1
  for (int i = 0; i < 16; ++i) {
    const int t1 = 2 * i + 1, t2 = 2 * i + 2, t3 = 2 * i + 3;
    const bool more = (i < 15);
    // ---- P1: regs Am0,Bn0(T0) | stage A(t1)h0 | MFMA quad(0,0)
    LDA_PH(0, 0); LDB_PH(0, 0);
    STAGE_A(t1, 0);
    BARR; MMA_PH(0, 0); BARR;
    // ---- P2: regs Bn1(T0) | stage A(t1)h1 | quad(0,1)
    LDB_PH(0, 1);
    STAGE_A(t1, 1);
    BARR; MMA_PH(0, 1); BARR;
    // ---- P3: regs Am1(T0) | stage B(t2)h0 | quad(1,0)
    LDA_PH(0, 1);
    if (more) STAGE_B(t2, 0);
    BARR; MMA_PH(1, 0); BARR;
    // ---- P4: stage B(t2)h1 | vmcnt -> T1 resident | quad(1,1)
    if (more) { STAGE_B(t2, 1); VMCNT4; } else { VMCNT0; }
    BARR; MMA_PH(1, 1); BARR;
    // ---- P5: regs Am0,Bn0(T1) | stage A(t2)h0 | quad(0,0)
    LDA_PH(1, 0); LDB_PH(1, 0);
    if (more) STAGE_A(t2, 0);
    BARR; MMA_PH(0, 0); BARR;
    // ---- P6: regs Bn1(T1) | stage A(t2)h1 | quad(0,1)
    LDB_PH(1, 1);
    if (more) STAGE_A(t2, 1);
    BARR; MMA_PH(0, 1); BARR;
    // ---- P7: regs Am1(T1) | stage B(t3)h0 | quad(1,0)
    LDA_PH(1, 1);
    if (more) STAGE_B(t3, 0);
    BARR; MMA_PH(1, 0); BARR;
    // ---- P8: stage B(t3)h1 | vmcnt -> next T0 resident | quad(1,1)
    if (more) { STAGE_B(t3, 1); VMCNT4; }
    BARR; MMA_PH(1, 1); BARR;
  }

  if (MODE == 0) {
#pragma unroll
    for (int mi = 0; mi < 8; ++mi) {
#pragma unroll
      for (int ni = 0; ni < 4; ++ni) {
        const int n = n0 + wc * 64 + ni * 16 + lr;
        const int sec = n >> 11, nn = n & 2047;
        const int h = nn >> 7, d = nn & 127;
#pragma unroll
        for (int r = 0; r < 4; ++r) {
          const int m = m0 + wr * 128 + mi * 16 + lg * 4 + r;
          const int b = m >> 11, t = m & 2047;
          float val = acc[mi][ni][r];
          if (sec < 2) {
            // RoPE pair (d, d^1) sits in lane l^1 (D-frag col = lane&15)
            float partner = __shfl_xor(val, 1);
            const int fi = d >> 1;
            float cth = ctab[t * 64 + fi], sth = stab[t * 64 + fi];
            float ov = (d & 1) ? (val * cth + partner * sth)
                               : (val * cth - partner * sth);
            if (sec == 0) ov *= 0.08838834764831845f;  // 1/sqrt(128) into q
            bf16_t* dst = (sec == 0) ? qws : kws;
            dst[((size_t)(b * H_NUM + h) * T_SEQ + t) * HD + d] = (bf16_t)ov;
          } else {
            vtws[((size_t)(b * H_NUM + h) * HD + d) * T_SEQ + t] = (bf16_t)val;
          }
        }
      }
    }
  } else {
#pragma unroll
    for (int mi = 0; mi < 8; ++mi)
#pragma unroll
      for (int ni = 0; ni < 4; ++ni) {
        const int n = n0 + wc * 64 + ni * 16 + lr;
#pragma unroll
        for (int r = 0; r < 4; ++r) {
          const int m = m0 + wr * 128 + mi * 16 + lg * 4 + r;
          outF[(size_t)m * C_DIM + n] = acc[mi][ni][r];
        }
      }
  }
}

// ---------------- causal flash attention (v2.1, unchanged) ----------------
__global__ __launch_bounds__(256, 2)
void attention_kernel(const bf16_t* __restrict__ qg, const bf16_t* __restrict__ kg,
                      const bf16_t* __restrict__ vtg, bf16_t* __restrict__ yg) {
  const int tid = threadIdx.x;
  const int l = tid & 63, w = tid >> 6;
  const int lg = l >> 4, lr = l & 15;
  const int bh = blockIdx.y;
  const int b = bh >> 4, h = bh & 15;

  __shared__ __align__(16) bf16_t lk[2][64][128];
  __shared__ __align__(16) bf16_t lp[4][16][72];   // per-wave P bounce, +8 pad

  const bf16_t* qp = qg + (size_t)bh * T_SEQ * HD;
  const bf16_t* kp = kg + (size_t)bh * T_SEQ * HD;
  const bf16_t* vp = vtg + (size_t)bh * HD * T_SEQ;

#pragma unroll 1
  for (int half = 0; half < 2; ++half) {
    const int qt = (half == 0) ? (31 - blockIdx.x) : blockIdx.x;
    const int qbase = qt * 64 + w * 16;

    bf16x8 qf[4];
#pragma unroll
    for (int dk = 0; dk < 4; ++dk)
      qf[dk] = *reinterpret_cast<const bf16x8*>(qp + (size_t)(qbase + lr) * HD + dk * 32 + lg * 8);

    f32x4 o[8] = {};
    float mrun[4], lrun[4];
#pragma unroll
    for (int r = 0; r < 4; ++r) { mrun[r] = -1e30f; lrun[r] = 0.f; }

    bf16x8 kreg[4];
#pragma unroll
    for (int c = 0; c < 4; ++c) {
      int p = tid + c * 256, row = p >> 4, ch = p & 15;
      kreg[c] = *reinterpret_cast<const bf16x8*>(kp + (size_t)row * HD + ch * 8);
    }
    __syncthreads();
#pragma unroll
    for (int c = 0; c < 4; ++c) {
      int p = tid + c * 256, row = p >> 4, ch = (p & 15) ^ (row & 7);
      *reinterpret_cast<bf16x8*>(&lk[0][row][ch * 8]) = kreg[c];
    }
    __syncthreads();

#pragma unroll 1
    for (int kt = 0; kt <= qt; ++kt) {
      const int cur = kt & 1;
      const int kv0 = kt * 64;

      bf16x8 vf[16];
#pragma unroll
      for (int cc = 0; cc < 8; ++cc)
#pragma unroll
        for (int ks = 0; ks < 2; ++ks)
          vf[cc * 2 + ks] = *reinterpret_cast<const bf16x8*>(
              vp + (size_t)(cc * 16 + lr) * T_SEQ + kv0 + ks * 32 + lg * 8);

      if (kt < qt) {
#pragma unroll
        for (int c = 0; c < 4; ++c) {
          int p = tid + c * 256, row = p >> 4, ch = p & 15;
          kreg[c] = *reinterpret_cast<const bf16x8*>(
              kp + (size_t)(kv0 + 64 + row) * HD + ch * 8);
        }
      }

      f32x4 sacc[4] = {};
#pragma unroll
      for (int dk = 0; dk < 4; ++dk) {
        bf16x8 kf[4];
#pragma unroll
        for (int f = 0; f < 4; ++f) {
          const int ch = (dk * 4 + lg) ^ (lr & 7);
          kf[f] = *reinterpret_cast<const bf16x8*>(&lk[cur][f * 16 + lr][ch * 8]);
        }
#pragma unroll
        for (int f = 0; f < 4; ++f)
          sacc[f] = __builtin_amdgcn_mfma_f32_16x16x32_bf16(qf[dk], kf[f], sacc[f], 0, 0, 0);
      }

      if (kt == qt) {
#pragma unroll
        for (int f = 0; f < 4; ++f)
#pragma unroll
          for (int r = 0; r < 4; ++r)
            if (kv0 + f * 16 + lr > qbase + lg * 4 + r) sacc[f][r] = -1e30f;
      }

      float sf[4];
#pragma unroll
      for (int r = 0; r < 4; ++r) {
        float mx = fmaxf(fmaxf(sacc[0][r], sacc[1][r]), fmaxf(sacc[2][r], sacc[3][r]));
        mx = fmaxf(mx, __shfl_xor(mx, 1));
        mx = fmaxf(mx, __shfl_xor(mx, 2));
        mx = fmaxf(mx, __shfl_xor(mx, 4));
        mx = fmaxf(mx, __shfl_xor(mx, 8));
        float mnew = fmaxf(mrun[r], mx);
        sf[r] = __expf(mrun[r] - mnew);
        mrun[r] = mnew;
      }
#pragma unroll
      for (int f = 0; f < 4; ++f)
#pragma unroll
        for (int r = 0; r < 4; ++r)
          sacc[f][r] = __expf(sacc[f][r] - mrun[r]);
#pragma unroll
      for (int r = 0; r < 4; ++r) {
        float s = sacc[0][r] + sacc[1][r] + sacc[2][r] + sacc[3][r];
        s += __shfl_xor(s, 1); s += __shfl_xor(s, 2);
        s += __shfl_xor(s, 4); s += __shfl_xor(s, 8);
        lrun[r] = lrun[r] * sf[r] + s;
      }
#pragma unroll
      for (int cc = 0; cc < 8; ++cc)
#pragma unroll
        for (int r = 0; r < 4; ++r)
          o[cc][r] *= sf[r];

#pragma unroll
      for (int f = 0; f < 4; ++f)
#pragma unroll
        for (int r = 0; r < 4; ++r)
          lp[w][lg * 4 + r][f * 16 + lr] = (bf16_t)sacc[f][r];

#pragma unroll
      for (int ks = 0; ks < 2; ++ks) {
        bf16x8 pf = *reinterpret_cast<const bf16x8*>(&lp[w][lr][ks * 32 + lg * 8]);
#pragma unroll
        for (int cc = 0; cc < 8; ++cc)
          o[cc] = __builtin_amdgcn_mfma_f32_16x16x32_bf16(pf, vf[cc * 2 + ks], o[cc], 0, 0, 0);
      }

      if (kt < qt) {
#pragma unroll
        for (int c = 0; c < 4; ++c) {
          int p = tid + c * 256, row = p >> 4, ch = (p & 15) ^ (row & 7);
          *reinterpret_cast<bf16x8*>(&lk[cur ^ 1][row][ch * 8]) = kreg[c];
        }
      }
      __syncthreads();
    }

#pragma unroll
    for (int r = 0; r < 4; ++r) lrun[r] = 1.0f / lrun[r];
#pragma unroll
    for (int cc = 0; cc < 8; ++cc)
#pragma unroll
      for (int r = 0; r < 4; ++r) {
        int t = qbase + lg * 4 + r;
        float val = o[cc][r] * lrun[r];
        yg[((size_t)(b * T_SEQ + t)) * C_DIM + h * HD + cc * 16 + lr] = (bf16_t)val;
      }
  }
}

// ---------------- launch ----------------
extern "C" void kernel_launch(void* const* d_in, const int* in_sizes, int n_in,
                              void* d_out, int out_size, void* d_ws, size_t ws_size,
                              hipStream_t stream) {
  (void)in_sizes; (void)n_in; (void)out_size; (void)ws_size;
  const float* x     = (const float*)d_in[0];
  const float* Wqkv  = (const float*)d_in[1];
  const float* Wproj = (const float*)d_in[2];
  float* out = (float*)d_out;

  char* ws = (char*)d_ws;
  float*  ctab   = (float*)(ws + 0);          // 512 KB
  float*  stab   = (float*)(ws + 524288);     // 512 KB
  bf16_t* xb     = (bf16_t*)(ws + 1048576);   // 16 MB
  bf16_t* wqkvT  = (bf16_t*)(ws + 17825792);  // 24 MB  [6144][2048]
  bf16_t* wprojT = (bf16_t*)(ws + 42991616);  // 8 MB   [2048][2048]
  bf16_t* qws    = (bf16_t*)(ws + 51380224);  // 16 MB  [b][h][t][d]
  bf16_t* kws    = (bf16_t*)(ws + 68157440);  // 16 MB  [b][h][t][d]
  bf16_t* vtws   = (bf16_t*)(ws + 84934656);  // 16 MB  [b][h][d][t]
  bf16_t* yws    = (bf16_t*)(ws + 101711872); // 16 MB  [b*t][h*d]

  rope_table_kernel<<<512, 256, 0, stream>>>(ctab, stab);
  convert_bf16_kernel<<<8192, 256, 0, stream>>>(x, xb, 2097152);
  transpose_convert_kernel<<<dim3(192, 64), dim3(32, 8), 0, stream>>>(Wqkv, wqkvT, 2048, 6144);
  transpose_convert_kernel<<<dim3(64, 64), dim3(32, 8), 0, stream>>>(Wproj, wprojT, 2048, 2048);

  // GEMM1: M=4096, N=6144 -> 16 x 24 = 384 blocks (384 % 8 == 0)
  gemm256_kernel<0><<<384, 512, 0, stream>>>(
      xb, wqkvT, nullptr, qws, kws, vtws, ctab, stab, 24);

  attention_kernel<<<dim3(16, 32), 256, 0, stream>>>(qws, kws, vtws, yws);

  // GEMM2: M=4096, N=2048 -> 16 x 8 = 128 blocks (128 % 8 == 0)
  gemm256_kernel<1><<<128, 512, 0, stream>>>(
      yws, wprojT, out, nullptr, nullptr, nullptr, nullptr, nullptr, 8);
}

// Round 7
// 359.452 us; speedup vs baseline: 1.1067x; 1.1067x over previous
//
#include <hip/hip_runtime.h>
#include <cmath>

typedef __bf16 bf16_t;
typedef __bf16 bf16x8 __attribute__((ext_vector_type(8)));
typedef __bf16 bf16x4 __attribute__((ext_vector_type(4)));
typedef float f32x4 __attribute__((ext_vector_type(4)));

#define T_SEQ 2048
#define C_DIM 2048
#define H_NUM 16
#define HD    128
#define KK    2048  // reduction dim for both GEMMs

// ---------------- RoPE cos/sin table: [T][64] ----------------
__global__ void rope_table_kernel(float* __restrict__ ct, float* __restrict__ st) {
  int idx = blockIdx.x * 256 + threadIdx.x;   // T*64 = 131072
  int t = idx >> 6, i = idx & 63;
  double invf = pow(10000.0, -(double)i / 64.0);  // base^(-2i/hd)
  float ang = (float)t * (float)invf;             // fp32 rounding like reference
  ct[idx] = cosf(ang);
  st[idx] = sinf(ang);
}

// ---------------- fp32 -> bf16 elementwise ----------------
__global__ void convert_bf16_kernel(const float* __restrict__ in, bf16_t* __restrict__ out, int n4) {
  int i = blockIdx.x * 256 + threadIdx.x;
  if (i >= n4) return;
  const float4 v = reinterpret_cast<const float4*>(in)[i];
  bf16x4 o;
  o[0] = (bf16_t)v.x; o[1] = (bf16_t)v.y; o[2] = (bf16_t)v.z; o[3] = (bf16_t)v.w;
  reinterpret_cast<bf16x4*>(out)[i] = o;
}

// ---------------- transpose+convert: in[R][Cc] f32 -> out[Cc][R] bf16 ----------------
__global__ void transpose_convert_kernel(const float* __restrict__ in, bf16_t* __restrict__ out,
                                         int R, int Cc) {
  __shared__ __align__(16) bf16_t tile[32][33];
  int c0 = blockIdx.x * 32, r0 = blockIdx.y * 32;
  int tx = threadIdx.x, ty = threadIdx.y;
#pragma unroll
  for (int i = 0; i < 4; ++i)
    tile[ty + 8 * i][tx] = (bf16_t)in[(size_t)(r0 + ty + 8 * i) * Cc + c0 + tx];
  __syncthreads();
#pragma unroll
  for (int i = 0; i < 4; ++i)
    out[(size_t)(c0 + ty + 8 * i) * R + r0 + tx] = tile[tx][ty + 8 * i];
}

// ---------------- GEMM: A[M][K] bf16 @ Bt[N][K] bf16 -> epilogue ----------------
// Round-3 structure (best measured): 128x128 tile, BK=64, 4 waves, register
// staging with one-tile-ahead prefetch, 2 barriers/K-step.
// Change vs round 3: LDS tiles are [128][64] (no pad) with XOR chunk layout —
// write dest chunk = (p&7)^(row&7), read chunk = (ks*4+lg)^(lr&7) — the
// round-5-verified conflict-free involution (kills round-3's 12.6M conflicts).
// MODE 0: qkv epilogue: RoPE on q,k (scale*log2e folded into q for exp2
//         softmax), q,k as [b][h][t][d], v transposed [b][h][d][t].
// MODE 1: plain fp32 output to outF[M][C_DIM].
template <int MODE>
__global__ __launch_bounds__(256, 2)
void gemm_bf16_kernel(const bf16_t* __restrict__ A, const bf16_t* __restrict__ Bt,
                      float* __restrict__ outF,
                      bf16_t* __restrict__ qws, bf16_t* __restrict__ kws,
                      bf16_t* __restrict__ vtws,
                      const float* __restrict__ ctab, const float* __restrict__ stab) {
  const int tid = threadIdx.x;
  const int l = tid & 63, w = tid >> 6;
  const int wr = w >> 1, wc = w & 1;
  const int m0 = blockIdx.y * 128, n0 = blockIdx.x * 128;
  const int lg = l >> 4, lr = l & 15;

  __shared__ __align__(16) bf16_t la[128][64];
  __shared__ __align__(16) bf16_t lb[128][64];

  f32x4 acc[4][4] = {};
  bf16x8 ra[4], rb[4];

  const bf16_t* Ab = A + (size_t)m0 * KK;
  const bf16_t* Bb = Bt + (size_t)n0 * KK;

#pragma unroll
  for (int c = 0; c < 4; ++c) {
    int p = tid + c * 256, row = p >> 3, kc = p & 7;
    ra[c] = *reinterpret_cast<const bf16x8*>(Ab + (size_t)row * KK + kc * 8);
    rb[c] = *reinterpret_cast<const bf16x8*>(Bb + (size_t)row * KK + kc * 8);
  }

  for (int kt = 0; kt < KK / 64; ++kt) {
    __syncthreads();  // previous tile's reads done
#pragma unroll
    for (int c = 0; c < 4; ++c) {
      int p = tid + c * 256, row = p >> 3;
      int kcw = (p & 7) ^ (row & 7);   // XOR layout: phys chunk holds global^row
      *reinterpret_cast<bf16x8*>(&la[row][kcw * 8]) = ra[c];
      *reinterpret_cast<bf16x8*>(&lb[row][kcw * 8]) = rb[c];
    }
    __syncthreads();
    if (kt + 1 < KK / 64) {  // prefetch next tile; latency hides under MFMAs
#pragma unroll
      for (int c = 0; c < 4; ++c) {
        int p = tid + c * 256, row = p >> 3, kc = p & 7;
        ra[c] = *reinterpret_cast<const bf16x8*>(Ab + (size_t)row * KK + (kt + 1) * 64 + kc * 8);
        rb[c] = *reinterpret_cast<const bf16x8*>(Bb + (size_t)row * KK + (kt + 1) * 64 + kc * 8);
      }
    }
#pragma unroll
    for (int ks = 0; ks < 2; ++ks) {
      bf16x8 af[4], bfr[4];
      const int pc = ((ks * 4 + lg) ^ (lr & 7)) * 8;  // matching read XOR
#pragma unroll
      for (int i = 0; i < 4; ++i) {
        af[i]  = *reinterpret_cast<const bf16x8*>(&la[wr * 64 + i * 16 + lr][pc]);
        bfr[i] = *reinterpret_cast<const bf16x8*>(&lb[wc * 64 + i * 16 + lr][pc]);
      }
#pragma unroll
      for (int mi = 0; mi < 4; ++mi)
#pragma unroll
        for (int ni = 0; ni < 4; ++ni)
          acc[mi][ni] = __builtin_amdgcn_mfma_f32_16x16x32_bf16(af[mi], bfr[ni], acc[mi][ni], 0, 0, 0);
    }
  }

  if (MODE == 0) {
    const int sec = n0 >> 11;           // 0=q 1=k 2=v (block never crosses sections)
    const int h = (n0 & 2047) >> 7;     // one head per 128-col block
#pragma unroll
    for (int mi = 0; mi < 4; ++mi) {
#pragma unroll
      for (int ni = 0; ni < 4; ++ni) {
        const int d = wc * 64 + ni * 16 + lr;   // 0..127
#pragma unroll
        for (int r = 0; r < 4; ++r) {
          const int m = m0 + wr * 64 + mi * 16 + lg * 4 + r;
          const int b = m >> 11, t = m & 2047;
          float val = acc[mi][ni][r];
          if (sec < 2) {
            // RoPE pair (d, d^1) sits in lane l^1 (D-frag col = lane&15)
            float partner = __shfl_xor(val, 1);
            const int fi = d >> 1;
            float cth = ctab[t * 64 + fi], sth = stab[t * 64 + fi];
            float ov = (d & 1) ? (val * cth + partner * sth)
                               : (val * cth - partner * sth);
            // q scale = (1/sqrt(128)) * log2(e): softmax runs in exp2 domain
            if (sec == 0) ov *= 0.127517445f;
            bf16_t* dst = (sec == 0) ? qws : kws;
            dst[((size_t)(b * H_NUM + h) * T_SEQ + t) * HD + d] = (bf16_t)ov;
          } else {
            // v stored transposed [b][h][d][t] so PV B-operand is kv-contiguous
            vtws[((size_t)(b * H_NUM + h) * HD + d) * T_SEQ + t] = (bf16_t)val;
          }
        }
      }
    }
  } else {
#pragma unroll
    for (int mi = 0; mi < 4; ++mi)
#pragma unroll
      for (int ni = 0; ni < 4; ++ni) {
        const int n = n0 + wc * 64 + ni * 16 + lr;
#pragma unroll
        for (int r = 0; r < 4; ++r) {
          const int m = m0 + wr * 64 + mi * 16 + lg * 4 + r;
          outF[(size_t)m * C_DIM + n] = acc[mi][ni][r];
        }
      }
  }
}

// ---------------- causal flash attention (v3) ----------------
// v2.1 structure (verified) + exp2-domain softmax (q pre-scaled by log2e at
// the GEMM1 epilogue) + defer-max rescale (T13): skip the O/l rescale unless
// any row's tile-max exceeds the running max by >8 (log2 units); P is then
// bounded by 2^8, which f32 accumulators tolerate trivially.
__global__ __launch_bounds__(256, 2)
void attention_kernel(const bf16_t* __restrict__ qg, const bf16_t* __restrict__ kg,
                      const bf16_t* __restrict__ vtg, bf16_t* __restrict__ yg) {
  const int tid = threadIdx.x;
  const int l = tid & 63, w = tid >> 6;
  const int lg = l >> 4, lr = l & 15;
  const int bh = blockIdx.y;
  const int b = bh >> 4, h = bh & 15;

  __shared__ __align__(16) bf16_t lk[2][64][128];
  __shared__ __align__(16) bf16_t lp[4][16][72];   // per-wave P bounce, +8 pad

  const bf16_t* qp = qg + (size_t)bh * T_SEQ * HD;
  const bf16_t* kp = kg + (size_t)bh * T_SEQ * HD;
  const bf16_t* vp = vtg + (size_t)bh * HD * T_SEQ;

#pragma unroll 1
  for (int half = 0; half < 2; ++half) {
    const int qt = (half == 0) ? (31 - blockIdx.x) : blockIdx.x;
    const int qbase = qt * 64 + w * 16;

    bf16x8 qf[4];
#pragma unroll
    for (int dk = 0; dk < 4; ++dk)
      qf[dk] = *reinterpret_cast<const bf16x8*>(qp + (size_t)(qbase + lr) * HD + dk * 32 + lg * 8);

    f32x4 o[8] = {};
    float mrun[4], lrun[4];
#pragma unroll
    for (int r = 0; r < 4; ++r) { mrun[r] = -1e30f; lrun[r] = 0.f; }

    bf16x8 kreg[4];
#pragma unroll
    for (int c = 0; c < 4; ++c) {
      int p = tid + c * 256, row = p >> 4, ch = p & 15;
      kreg[c] = *reinterpret_cast<const bf16x8*>(kp + (size_t)row * HD + ch * 8);
    }
    __syncthreads();
#pragma unroll
    for (int c = 0; c < 4; ++c) {
      int p = tid + c * 256, row = p >> 4, ch = (p & 15) ^ (row & 7);
      *reinterpret_cast<bf16x8*>(&lk[0][row][ch * 8]) = kreg[c];
    }
    __syncthreads();

#pragma unroll 1
    for (int kt = 0; kt <= qt; ++kt) {
      const int cur = kt & 1;
      const int kv0 = kt * 64;

      // 1) V fragments for THIS tile: issue first (needed mid-iteration)
      bf16x8 vf[16];
#pragma unroll
      for (int cc = 0; cc < 8; ++cc)
#pragma unroll
        for (int ks = 0; ks < 2; ++ks)
          vf[cc * 2 + ks] = *reinterpret_cast<const bf16x8*>(
              vp + (size_t)(cc * 16 + lr) * T_SEQ + kv0 + ks * 32 + lg * 8);

      // 2) K prefetch for NEXT tile (stays in flight past the V wait)
      if (kt < qt) {
#pragma unroll
        for (int c = 0; c < 4; ++c) {
          int p = tid + c * 256, row = p >> 4, ch = p & 15;
          kreg[c] = *reinterpret_cast<const bf16x8*>(
              kp + (size_t)(kv0 + 64 + row) * HD + ch * 8);
        }
      }

      // 3) S = Q K^T from lk[cur] (swizzled reads; S is in log2 units)
      f32x4 sacc[4] = {};
#pragma unroll
      for (int dk = 0; dk < 4; ++dk) {
        bf16x8 kf[4];
#pragma unroll
        for (int f = 0; f < 4; ++f) {
          const int ch = (dk * 4 + lg) ^ (lr & 7);
          kf[f] = *reinterpret_cast<const bf16x8*>(&lk[cur][f * 16 + lr][ch * 8]);
        }
#pragma unroll
        for (int f = 0; f < 4; ++f)
          sacc[f] = __builtin_amdgcn_mfma_f32_16x16x32_bf16(qf[dk], kf[f], sacc[f], 0, 0, 0);
      }

      if (kt == qt) {  // only the diagonal tile needs the causal mask
#pragma unroll
        for (int f = 0; f < 4; ++f)
#pragma unroll
          for (int r = 0; r < 4; ++r)
            if (kv0 + f * 16 + lr > qbase + lg * 4 + r) sacc[f][r] = -1e30f;
      }

      // 4) online softmax (exp2 domain), defer-max: rescale only on big growth
      float mx[4];
#pragma unroll
      for (int r = 0; r < 4; ++r) {
        float m = fmaxf(fmaxf(sacc[0][r], sacc[1][r]), fmaxf(sacc[2][r], sacc[3][r]));
        m = fmaxf(m, __shfl_xor(m, 1));
        m = fmaxf(m, __shfl_xor(m, 2));
        m = fmaxf(m, __shfl_xor(m, 4));
        m = fmaxf(m, __shfl_xor(m, 8));
        mx[r] = m;
      }
      bool grow = (mx[0] > mrun[0] + 8.f) || (mx[1] > mrun[1] + 8.f) ||
                  (mx[2] > mrun[2] + 8.f) || (mx[3] > mrun[3] + 8.f);
      if (__any(grow)) {
#pragma unroll
        for (int r = 0; r < 4; ++r) {
          float mnew = fmaxf(mrun[r], mx[r]);
          float sf = exp2f(mrun[r] - mnew);
          mrun[r] = mnew;
          lrun[r] *= sf;
#pragma unroll
          for (int cc = 0; cc < 8; ++cc) o[cc][r] *= sf;
        }
      }
#pragma unroll
      for (int f = 0; f < 4; ++f)
#pragma unroll
        for (int r = 0; r < 4; ++r)
          sacc[f][r] = exp2f(sacc[f][r] - mrun[r]);   // bounded by 2^8
#pragma unroll
      for (int r = 0; r < 4; ++r) {
        float s = sacc[0][r] + sacc[1][r] + sacc[2][r] + sacc[3][r];
        s += __shfl_xor(s, 1); s += __shfl_xor(s, 2);
        s += __shfl_xor(s, 4); s += __shfl_xor(s, 8);
        lrun[r] += s;
      }

      // 5) P -> LDS (wave-private; lgkmcnt only, no barrier)
#pragma unroll
      for (int f = 0; f < 4; ++f)
#pragma unroll
        for (int r = 0; r < 4; ++r)
          lp[w][lg * 4 + r][f * 16 + lr] = (bf16_t)sacc[f][r];

      // 6) O += P V (V from registers)
#pragma unroll
      for (int ks = 0; ks < 2; ++ks) {
        bf16x8 pf = *reinterpret_cast<const bf16x8*>(&lp[w][lr][ks * 32 + lg * 8]);
#pragma unroll
        for (int cc = 0; cc < 8; ++cc)
          o[cc] = __builtin_amdgcn_mfma_f32_16x16x32_bf16(pf, vf[cc * 2 + ks], o[cc], 0, 0, 0);
      }

      // 7) write prefetched K into the other buffer; single barrier/iter
      if (kt < qt) {
#pragma unroll
        for (int c = 0; c < 4; ++c) {
          int p = tid + c * 256, row = p >> 4, ch = (p & 15) ^ (row & 7);
          *reinterpret_cast<bf16x8*>(&lk[cur ^ 1][row][ch * 8]) = kreg[c];
        }
      }
      __syncthreads();
    }

    // normalize + write y as [b][t][h*128+d] (GEMM2 A layout)
#pragma unroll
    for (int r = 0; r < 4; ++r) lrun[r] = 1.0f / lrun[r];
#pragma unroll
    for (int cc = 0; cc < 8; ++cc)
#pragma unroll
      for (int r = 0; r < 4; ++r) {
        int t = qbase + lg * 4 + r;
        float val = o[cc][r] * lrun[r];
        yg[((size_t)(b * T_SEQ + t)) * C_DIM + h * HD + cc * 16 + lr] = (bf16_t)val;
      }
  }
}

// ---------------- launch ----------------
extern "C" void kernel_launch(void* const* d_in, const int* in_sizes, int n_in,
                              void* d_out, int out_size, void* d_ws, size_t ws_size,
                              hipStream_t stream) {
  (void)in_sizes; (void)n_in; (void)out_size; (void)ws_size;
  const float* x     = (const float*)d_in[0];
  const float* Wqkv  = (const float*)d_in[1];
  const float* Wproj = (const float*)d_in[2];
  float* out = (float*)d_out;

  char* ws = (char*)d_ws;
  float*  ctab   = (float*)(ws + 0);          // 512 KB
  float*  stab   = (float*)(ws + 524288);     // 512 KB
  bf16_t* xb     = (bf16_t*)(ws + 1048576);   // 16 MB
  bf16_t* wqkvT  = (bf16_t*)(ws + 17825792);  // 24 MB  [6144][2048]
  bf16_t* wprojT = (bf16_t*)(ws + 42991616);  // 8 MB   [2048][2048]
  bf16_t* qws    = (bf16_t*)(ws + 51380224);  // 16 MB  [b][h][t][d]
  bf16_t* kws    = (bf16_t*)(ws + 68157440);  // 16 MB  [b][h][t][d]
  bf16_t* vtws   = (bf16_t*)(ws + 84934656);  // 16 MB  [b][h][d][t]
  bf16_t* yws    = (bf16_t*)(ws + 101711872); // 16 MB  [b*t][h*d]

  rope_table_kernel<<<512, 256, 0, stream>>>(ctab, stab);
  convert_bf16_kernel<<<8192, 256, 0, stream>>>(x, xb, 2097152);
  transpose_convert_kernel<<<dim3(192, 64), dim3(32, 8), 0, stream>>>(Wqkv, wqkvT, 2048, 6144);
  transpose_convert_kernel<<<dim3(64, 64), dim3(32, 8), 0, stream>>>(Wproj, wprojT, 2048, 2048);

  gemm_bf16_kernel<0><<<dim3(48, 32), 256, 0, stream>>>(
      xb, wqkvT, nullptr, qws, kws, vtws, ctab, stab);

  attention_kernel<<<dim3(16, 32), 256, 0, stream>>>(qws, kws, vtws, yws);

  gemm_bf16_kernel<1><<<dim3(16, 32), 256, 0, stream>>>(
      yws, wprojT, out, nullptr, nullptr, nullptr, nullptr, nullptr);
}